// Round 11
// baseline (460.802 us; speedup 1.0000x reference)
//
#include <hip/hip_runtime.h>
#include <math.h>

#define NN 100000
#define NE 1600000
#define ET (NE + NN)            // 1,700,000 edges incl. self-loops
#define NEG 0.2f
#define KP 192                  // padded K for MFMA (165 -> 192)
#define GEMM_BLKS (NN / 32)     // 3125
#define SLOTS 64                // fixed edge slots per node (P(deg>63) ~ 1e-25)
#define NPART 8                 // dst-range partitions
#define PART_SZ (NN / NPART)    // 12500
#define NCHUNK 1024
#define CH ((NE + NCHUNK - 1) / NCHUNK)   // 1563 edges per chunk
#define HS_BLKS (NPART * NCHUNK)          // 8192 histscat role blocks
#define LDA 200                 // LDS A-tile row stride in bf16 (400B rows)

typedef __attribute__((ext_vector_type(8))) short short8;
typedef __attribute__((ext_vector_type(4))) float floatx4;

// bf16 helpers (round-to-nearest-even)
__device__ __forceinline__ unsigned short f2bf(float f) {
    unsigned u = __float_as_uint(f);
    unsigned r = u + 0x7fffu + ((u >> 16) & 1u);
    return (unsigned short)(r >> 16);
}
__device__ __forceinline__ float bflo(unsigned x) { return __uint_as_float(x << 16); }
__device__ __forceinline__ float bfhi(unsigned x) { return __uint_as_float(x & 0xFFFF0000u); }

// ---------------- prep: Wt bf16 [256][KP], deg=1 + self-loop slot0 -----------
__global__ __launch_bounds__(256) void k_prep(const float* __restrict__ W,
                                              unsigned short* __restrict__ Wt,
                                              int* __restrict__ deg,
                                              int* __restrict__ esrc) {
    const int gid = blockIdx.x * 256 + threadIdx.x;
    const int G = gridDim.x * 256;
    for (int idx = gid; idx < 256 * KP; idx += G) {
        const int n = idx / KP, k = idx - n * KP;
        Wt[idx] = (k < 165) ? f2bf(W[k * 256 + n]) : (unsigned short)0;
    }
    // self-loop pre-placed at slot 0: removes 100K edges from the scatter
    for (int i = gid; i < NN; i += G) { deg[i] = 1; esrc[i << 6] = i; }
}

// ---------------- fused histscat + GEMM1 (block-role split) ------------------
// R9->R10 lesson: the scatter role is occupancy-scaled; every VGPR fed to the
// gemm role costs scatter waves (64 VGPR->41% occ->182us; ~48->~62%->~155us).
// R11: (a) half-tile gemm (acc[4] per 16-node half, A-tile LDS persists,
// Wt re-read L2-hot) + DIRECT h1 stores (LDS pack-transpose deleted; quads
// write contiguous 32B segments, L2 merges) -> ~40 VGPR, LDS 12.8KB,
// __launch_bounds__(256,6) for ~75% occ. Numerics bit-identical (same
// per-acc MFMA chains, same f2bf, same h1 bytes).
// (b) consecutive partition dispatch (p=b>>10, not b&7): resident scatter
// window covers ~2 partitions -> active esrc write-set ~6MB (not 25.6MB),
// write lines survive until a node's slots fill (temporal density via
// dispatch order -- the hypothesis R6's interleaved b&7 mapping couldn't test).
// R8 lesson: NOT cooperative; oversubscribed block churn is the TLP resource.
__global__ __launch_bounds__(256, 6) void k_hsgemm(const int* __restrict__ src,
                                                const int* __restrict__ dst,
                                                const float* __restrict__ x,
                                                const unsigned short* __restrict__ Wt,
                                                const float* __restrict__ att_s,
                                                const float* __restrict__ att_d,
                                                int* __restrict__ deg,
                                                int* __restrict__ esrc,
                                                unsigned short* __restrict__ h1,
                                                float* __restrict__ a_src,
                                                float* __restrict__ a_dst) {
    __shared__ __align__(16) unsigned short lds_a[32 * LDA];   // 12.8 KB A-tile
    const int t = threadIdx.x;
    const int b = blockIdx.x;

    if (b < HS_BLKS) {
        // ---- histscat role: consecutive partitions (R11b) ----
        const int p = b >> 10;               // partition 0..7, dispatch-ordered
        const int chunk = b & 1023;
        const int e0 = chunk * CH;
        const int e1 = (e0 + CH < NE) ? e0 + CH : NE;
        const int plo = p * PART_SZ, phi = plo + PART_SZ;
        for (int e = e0 + t; e < e1; e += 256) {
            const int d = dst[e];
            if (d >= plo && d < phi) {
                const int s = src[e];
                const int r = atomicAdd(&deg[d], 1);
                if (r < SLOTS) esrc[(d << 6) + r] = s;
            }
        }
        return;
    }

    // ---- gemm role: one 32-node tile, processed as two 16-node halves ----
    const int n0 = (b - HS_BLKS) * 32;

    // stage x rows (coalesced, convert once) + zero the K-pad
    for (int i = t; i < 32 * 165; i += 256) {
        const int n = i / 165, k = i - n * 165;
        lds_a[n * LDA + k] = f2bf(x[(size_t)(n0 + n) * 165 + k]);
    }
    for (int i = t; i < 32 * (LDA - 165); i += 256) {      // k = 165..LDA-1 -> 0
        const int n = i / (LDA - 165), k = 165 + (i - n * (LDA - 165));
        lds_a[n * LDA + k] = 0;
    }
    __syncthreads();

    const int lane = t & 63, hd = t >> 6;
    const int r16 = lane & 15, quad = lane >> 4;
    float asw[4], adw[4];
#pragma unroll
    for (int nn = 0; nn < 4; ++nn) {
        asw[nn] = att_s[hd * 64 + nn * 16 + r16];
        adw[nn] = att_d[hd * 64 + nn * 16 + r16];
    }

#pragma unroll
    for (int mm = 0; mm < 2; ++mm) {
        floatx4 acc[4];
        floatx4 zero4 = {0.0f, 0.0f, 0.0f, 0.0f};
#pragma unroll
        for (int nn = 0; nn < 4; ++nn) acc[nn] = zero4;

        const unsigned short* ar = lds_a + (mm * 16 + r16) * LDA;
#pragma unroll
        for (int ks = 0; ks < 6; ++ks) {
            const int kb = ks * 32 + quad * 8;
            short8 a = *(const short8*)(ar + kb);
#pragma unroll
            for (int nn = 0; nn < 4; ++nn) {   // single B-frag live (VGPR diet)
                short8 bf = *(const short8*)(Wt + (size_t)(hd * 64 + nn * 16 + r16) * KP + kb);
                acc[nn] = __builtin_amdgcn_mfma_f32_16x16x32_bf16(a, bf, acc[nn], 0, 0, 0);
            }
        }

        // attention scalars for this half
#pragma unroll
        for (int r = 0; r < 4; ++r) {
            float ps = acc[0][r] * asw[0] + acc[1][r] * asw[1] +
                       acc[2][r] * asw[2] + acc[3][r] * asw[3];
            float pd = acc[0][r] * adw[0] + acc[1][r] * adw[1] +
                       acc[2][r] * adw[2] + acc[3][r] * adw[3];
            ps += __shfl_xor(ps, 1); ps += __shfl_xor(ps, 2);
            ps += __shfl_xor(ps, 4); ps += __shfl_xor(ps, 8);
            pd += __shfl_xor(pd, 1); pd += __shfl_xor(pd, 2);
            pd += __shfl_xor(pd, 4); pd += __shfl_xor(pd, 8);
            if (r16 == 0) {
                const int node = n0 + mm * 16 + quad * 4 + r;
                a_src[node * 4 + hd] = ps;
                a_dst[node * 4 + hd] = pd;
            }
        }

        // direct bf16x2 h1 store (pack via shfl pair; no LDS transpose)
#pragma unroll
        for (int nn = 0; nn < 4; ++nn)
#pragma unroll
            for (int r = 0; r < 4; ++r) {
                const float v = acc[nn][r];
                const float o = __shfl_xor(v, 1);
                if ((lane & 1) == 0) {
                    const unsigned pk = (unsigned)f2bf(v) | ((unsigned)f2bf(o) << 16);
                    const int node = n0 + mm * 16 + quad * 4 + r;
                    *(unsigned*)(h1 + (size_t)node * 256 + hd * 64 + nn * 16 + r16) = pk;
                }
            }
    }
}

// ---------------- layer-1 aggregation ---------------------------------------
// wave per node; padded 64-slot edge table (beg = n<<6, cnt = deg[n]).
// NOTE (R1/R2 lessons): this 32-VGPR guarded schedule is a measured local
// optimum. Hand-batched gathers (+24 VGPR) -> occupancy 78->40%, slower.
// Unguarded loads + __launch_bounds__(256,8) -> acc[] spill (555 MB scratch
// writes), 2x slower. TLP is doing the latency hiding; leave the guard alone.
// R5: 4-way grid split costs ~45us -> single launch. R8: cooperative mega-
// kernel (capped resident grid) -> 2.8x slower; keep standalone.
__global__ __launch_bounds__(256) void k_l1agg(const unsigned short* __restrict__ h1,
                                               const float* __restrict__ a_src,
                                               const float* __restrict__ a_dst,
                                               const int* __restrict__ deg,
                                               const int* __restrict__ esrc,
                                               const float* __restrict__ b1,
                                               const float* __restrict__ W2,
                                               const float* __restrict__ att_s2,
                                               const float* __restrict__ att_d2,
                                               float4* __restrict__ node2) {
    const int t = threadIdx.x;
    const int n = blockIdx.x * 4 + (t >> 6);
    const int l = t & 63;
    const int q = l >> 4;       // quarter 0..3 (phase B)
    const int sl = l & 15;      // lane in quarter
    const int head = sl >> 2;
    const int c0 = sl * 16;
    const int el = l >> 2;      // phase-A edge slot 0..15
    const int hl = l & 3;       // phase-A head
    const int dg = deg[n];
    const int ebase = n << 6;
    const float4 ad4 = *(const float4*)&a_dst[n * 4];
    const float adh = (hl == 0) ? ad4.x : (hl == 1) ? ad4.y : (hl == 2) ? ad4.z : ad4.w;

    float ssum = 0.0f;
    float acc[16];
#pragma unroll
    for (int c = 0; c < 16; ++c) acc[c] = 0.0f;

    for (int base = 0; base < dg; base += 16) {
        const int cnt = dg - base;             // wave-uniform, > 0
        const int iters = (cnt < 16) ? cnt : 16;
        int sA = 0; float pA = 0.0f;
        if (el < cnt) {                        // phase A: 16 edges x 4 heads
            sA = esrc[ebase + base + el];
            const float a = a_src[sA * 4 + hl] + adh;
            const float e = (a > 0.0f) ? a : NEG * a;
            pA = __expf(e);
        }
#pragma unroll
        for (int jb = 0; jb < 16; jb += 4) {   // uniform 4 iterations, unrolled
            const int j = jb + q;              // this quarter's edge slot (<=15)
            const int s = __shfl(sA, j << 2);
            const float p = __shfl(pA, (j << 2) | head);
            if (j < iters) {                   // divergent guard: no cross-lane ops inside
                ssum += p;
                const unsigned ho = ((unsigned)s << 8) + c0;
                const uint4 hv0 = *(const uint4*)(h1 + ho);
                const uint4 hv1 = *(const uint4*)(h1 + ho + 8);
                acc[0]  += p * bflo(hv0.x); acc[1]  += p * bfhi(hv0.x);
                acc[2]  += p * bflo(hv0.y); acc[3]  += p * bfhi(hv0.y);
                acc[4]  += p * bflo(hv0.z); acc[5]  += p * bfhi(hv0.z);
                acc[6]  += p * bflo(hv0.w); acc[7]  += p * bfhi(hv0.w);
                acc[8]  += p * bflo(hv1.x); acc[9]  += p * bfhi(hv1.x);
                acc[10] += p * bflo(hv1.y); acc[11] += p * bfhi(hv1.y);
                acc[12] += p * bflo(hv1.z); acc[13] += p * bfhi(hv1.z);
                acc[14] += p * bflo(hv1.w); acc[15] += p * bfhi(hv1.w);
            }
        }
    }
    // merge quarters (lanes with same sl share channel set; quarter bits = 4,5)
    ssum += __shfl_xor(ssum, 16); ssum += __shfl_xor(ssum, 32);
#pragma unroll
    for (int c = 0; c < 16; ++c) {
        acc[c] += __shfl_xor(acc[c], 16);
        acc[c] += __shfl_xor(acc[c], 32);
    }
    const float inv = 1.0f / ssum;
    float p0 = 0.0f, p1 = 0.0f;
#pragma unroll
    for (int c = 0; c < 16; ++c) {
        const float v = fmaxf(acc[c] * inv + b1[c0 + c], 0.0f);
        p0 += v * W2[(c0 + c) * 2 + 0];
        p1 += v * W2[(c0 + c) * 2 + 1];
    }
    if (q) { p0 = 0.0f; p1 = 0.0f; }
#pragma unroll
    for (int off = 32; off; off >>= 1) {
        p0 += __shfl_down(p0, off);
        p1 += __shfl_down(p1, off);
    }
    if (l == 0) {
        const float as2v = p0 * att_s2[0] + p1 * att_s2[1];
        const float ad2v = p0 * att_d2[0] + p1 * att_d2[1];
        node2[n] = make_float4(p0, p1, as2v, ad2v);
    }
}

// ---------------- layer-2 aggregation + log_softmax (16 lanes per node) -----
__global__ __launch_bounds__(256) void k_l2agg(const float4* __restrict__ node2,
                                               const int* __restrict__ deg,
                                               const int* __restrict__ esrc,
                                               const float* __restrict__ b2,
                                               float* __restrict__ out) {
    const int t = threadIdx.x;
    const int l = t & 63;
    const int g = l >> 4;                       // node within wave (0..3)
    const int i = l & 15;                       // lane within node group
    const int n = blockIdx.x * 16 + (t >> 6) * 4 + g;
    const int dg = deg[n];
    const int ebase = n << 6;
    const float adst = node2[n].w;
    float ssum = 0.0f, a0 = 0.0f, a1 = 0.0f;
    for (int idx = i; idx < dg; idx += 16) {
        const int s = esrc[ebase + idx];
        const float4 r = node2[s];
        const float a = r.z + adst;
        const float e = (a > 0.0f) ? a : NEG * a;
        const float p = __expf(e);
        ssum += p; a0 += p * r.x; a1 += p * r.y;
    }
#pragma unroll
    for (int off = 8; off; off >>= 1) {         // reduce within 16-lane group
        ssum += __shfl_xor(ssum, off);
        a0 += __shfl_xor(a0, off);
        a1 += __shfl_xor(a1, off);
    }
    if (i == 0) {
        const float inv = 1.0f / ssum;
        const float z0 = a0 * inv + b2[0];
        const float z1 = a1 * inv + b2[1];
        const float mz = fmaxf(z0, z1);
        const float lse = mz + __logf(__expf(z0 - mz) + __expf(z1 - mz));
        out[n * 2 + 0] = z0 - lse;
        out[n * 2 + 1] = z1 - lse;
    }
}

extern "C" void kernel_launch(void* const* d_in, const int* in_sizes, int n_in,
                              void* d_out, int out_size, void* d_ws, size_t ws_size,
                              hipStream_t stream) {
    const float* x    = (const float*)d_in[0];
    const int*   src  = (const int*)d_in[1];
    const int*   dst  = (const int*)d_in[2];
    const float* W1   = (const float*)d_in[3];
    const float* as1w = (const float*)d_in[4];
    const float* ad1w = (const float*)d_in[5];
    const float* b1   = (const float*)d_in[6];
    const float* W2   = (const float*)d_in[7];
    const float* as2w = (const float*)d_in[8];
    const float* ad2w = (const float*)d_in[9];
    const float* b2   = (const float*)d_in[10];
    float* out = (float*)d_out;

    char* w = (char*)d_ws;
    unsigned short* h1  = (unsigned short*)w; w += (size_t)NN * 256 * 2;  // 51.2 MB
    unsigned short* Wt  = (unsigned short*)w; w += (size_t)256 * KP * 2;  // 98 KB
    float* a_src = (float*)w; w += (size_t)NN * 4 * 4;
    float* a_dst = (float*)w; w += (size_t)NN * 4 * 4;
    float4* node2 = (float4*)w; w += (size_t)NN * 4 * 4;
    int* deg     = (int*)w;   w += (size_t)NN * 4;
    int* esrc    = (int*)w;   w += (size_t)NN * SLOTS * 4;                // 25.6 MB

    k_prep<<<512, 256, 0, stream>>>(W1, Wt, deg, esrc);
    k_hsgemm<<<HS_BLKS + GEMM_BLKS, 256, 0, stream>>>(src, dst, x, Wt, as1w, ad1w,
                                                      deg, esrc, h1, a_src, a_dst);
    k_l1agg<<<NN / 4, 256, 0, stream>>>(h1, a_src, a_dst, deg, esrc, b1, W2, as2w, ad2w, node2);
    k_l2agg<<<NN / 16, 256, 0, stream>>>(node2, deg, esrc, b2, out);
}

// Round 12
// 452.087 us; speedup vs baseline: 1.0193x; 1.0193x over previous
//
#include <hip/hip_runtime.h>
#include <math.h>

#define NN 100000
#define NE 1600000
#define ET (NE + NN)            // 1,700,000 edges incl. self-loops
#define NEG 0.2f
#define KP 192                  // padded K for MFMA (165 -> 192)
#define GEMM_BLKS (NN / 32)     // 3125
#define SLOTS 64                // fixed edge slots per node (P(deg>63) ~ 1e-25)
#define NPART 8                 // dst-range partitions
#define PART_SZ (NN / NPART)    // 12500
#define NCHUNK 1024
#define CH ((NE + NCHUNK - 1) / NCHUNK)   // 1563 edges per chunk
#define HS_BLKS (NPART * NCHUNK)          // 8192 histscat role blocks
#define LDA 200                 // LDS A-tile row stride in bf16 (400B rows)

typedef __attribute__((ext_vector_type(8))) short short8;
typedef __attribute__((ext_vector_type(4))) float floatx4;

// bf16 helpers (round-to-nearest-even)
__device__ __forceinline__ unsigned short f2bf(float f) {
    unsigned u = __float_as_uint(f);
    unsigned r = u + 0x7fffu + ((u >> 16) & 1u);
    return (unsigned short)(r >> 16);
}
__device__ __forceinline__ float bflo(unsigned x) { return __uint_as_float(x << 16); }
__device__ __forceinline__ float bfhi(unsigned x) { return __uint_as_float(x & 0xFFFF0000u); }

// ---------------- prep: Wt bf16 [256][KP], deg=1 + self-loop slot0 -----------
__global__ __launch_bounds__(256) void k_prep(const float* __restrict__ W,
                                              unsigned short* __restrict__ Wt,
                                              int* __restrict__ deg,
                                              int* __restrict__ esrc) {
    const int gid = blockIdx.x * 256 + threadIdx.x;
    const int G = gridDim.x * 256;
    for (int idx = gid; idx < 256 * KP; idx += G) {
        const int n = idx / KP, k = idx - n * KP;
        Wt[idx] = (k < 165) ? f2bf(W[k * 256 + n]) : (unsigned short)0;
    }
    // self-loop pre-placed at slot 0: removes 100K edges from the scatter
    for (int i = gid; i < NN; i += G) { deg[i] = 1; esrc[i << 6] = i; }
}

// ---------------- fused histscat + GEMM1 (block-role split) ------------------
// R9->R10 lesson: the scatter role is occupancy-scaled; every VGPR fed to the
// gemm role costs scatter waves (64 VGPR -> 41% occ -> 182us; ~48 -> 155us).
// R11 lesson: half-tile acc[4] does reach VGPR=40, but DIRECT 32B h1 stores
// amplify HBM writes (WRITE_SIZE 133->207MB, +45us) -- the LDS pack-transpose
// epilogue is load-bearing (full-line uint4 stores). R12 keeps the half-tile
// diet AND the transpose, in a separate [16][132] buffer (no A-tile aliasing).
// Partitioning stays b&7 (R11's b>>10 reorder unproven, reverted).
// R8 lesson: NOT cooperative; oversubscribed block churn is the TLP resource.
__global__ __launch_bounds__(256, 6) void k_hsgemm(const int* __restrict__ src,
                                                const int* __restrict__ dst,
                                                const float* __restrict__ x,
                                                const unsigned short* __restrict__ Wt,
                                                const float* __restrict__ att_s,
                                                const float* __restrict__ att_d,
                                                int* __restrict__ deg,
                                                int* __restrict__ esrc,
                                                unsigned short* __restrict__ h1,
                                                float* __restrict__ a_src,
                                                float* __restrict__ a_dst) {
    __shared__ __align__(16) unsigned short lds_a[32 * LDA];   // 12.8 KB A-tile
    __shared__ __align__(16) unsigned lds_t[16 * 132];         // 8.4 KB half-transpose
    const int t = threadIdx.x;
    const int b = blockIdx.x;

    if (b < HS_BLKS) {
        // ---- histscat role (R6 dst-range partitioned, b&7) ----
        const int p = b & 7;
        const int chunk = b >> 3;
        const int e0 = chunk * CH;
        const int e1 = (e0 + CH < NE) ? e0 + CH : NE;
        const int plo = p * PART_SZ, phi = plo + PART_SZ;
        for (int e = e0 + t; e < e1; e += 256) {
            const int d = dst[e];
            if (d >= plo && d < phi) {
                const int s = src[e];
                const int r = atomicAdd(&deg[d], 1);
                if (r < SLOTS) esrc[(d << 6) + r] = s;
            }
        }
        return;
    }

    // ---- gemm role: one 32-node tile, processed as two 16-node halves ----
    const int n0 = (b - HS_BLKS) * 32;

    // stage x rows (coalesced, convert once) + zero the K-pad
    for (int i = t; i < 32 * 165; i += 256) {
        const int n = i / 165, k = i - n * 165;
        lds_a[n * LDA + k] = f2bf(x[(size_t)(n0 + n) * 165 + k]);
    }
    for (int i = t; i < 32 * (LDA - 165); i += 256) {      // k = 165..LDA-1 -> 0
        const int n = i / (LDA - 165), k = 165 + (i - n * (LDA - 165));
        lds_a[n * LDA + k] = 0;
    }
    __syncthreads();

    const int lane = t & 63, hd = t >> 6;
    const int r16 = lane & 15, quad = lane >> 4;
    float asw[4], adw[4];
#pragma unroll
    for (int nn = 0; nn < 4; ++nn) {
        asw[nn] = att_s[hd * 64 + nn * 16 + r16];
        adw[nn] = att_d[hd * 64 + nn * 16 + r16];
    }

#pragma unroll
    for (int mm = 0; mm < 2; ++mm) {
        floatx4 acc[4];
        floatx4 zero4 = {0.0f, 0.0f, 0.0f, 0.0f};
#pragma unroll
        for (int nn = 0; nn < 4; ++nn) acc[nn] = zero4;

        const unsigned short* ar = lds_a + (mm * 16 + r16) * LDA;
#pragma unroll
        for (int ks = 0; ks < 6; ++ks) {
            const int kb = ks * 32 + quad * 8;
            short8 a = *(const short8*)(ar + kb);
#pragma unroll
            for (int nn = 0; nn < 4; ++nn) {   // single B-frag live (VGPR diet)
                short8 bf = *(const short8*)(Wt + (size_t)(hd * 64 + nn * 16 + r16) * KP + kb);
                acc[nn] = __builtin_amdgcn_mfma_f32_16x16x32_bf16(a, bf, acc[nn], 0, 0, 0);
            }
        }

        // attention scalars for this half
#pragma unroll
        for (int r = 0; r < 4; ++r) {
            float ps = acc[0][r] * asw[0] + acc[1][r] * asw[1] +
                       acc[2][r] * asw[2] + acc[3][r] * asw[3];
            float pd = acc[0][r] * adw[0] + acc[1][r] * adw[1] +
                       acc[2][r] * adw[2] + acc[3][r] * adw[3];
            ps += __shfl_xor(ps, 1); ps += __shfl_xor(ps, 2);
            ps += __shfl_xor(ps, 4); ps += __shfl_xor(ps, 8);
            pd += __shfl_xor(pd, 1); pd += __shfl_xor(pd, 2);
            pd += __shfl_xor(pd, 4); pd += __shfl_xor(pd, 8);
            if (r16 == 0) {
                const int node = n0 + mm * 16 + quad * 4 + r;
                a_src[node * 4 + hd] = ps;
                a_dst[node * 4 + hd] = pd;
            }
        }

        // pack to LDS (bf16x2), then full-line uint4 h1 stores (R10 epilogue,
        // per 16-row half; lds_t is distinct from lds_a -> no aliasing hazard)
#pragma unroll
        for (int nn = 0; nn < 4; ++nn)
#pragma unroll
            for (int r = 0; r < 4; ++r) {
                const float v = acc[nn][r];
                const float o = __shfl_xor(v, 1);
                if ((lane & 1) == 0) {
                    const unsigned pk = (unsigned)f2bf(v) | ((unsigned)f2bf(o) << 16);
                    lds_t[(quad * 4 + r) * 132 + hd * 32 + nn * 8 + (r16 >> 1)] = pk;
                }
            }
        __syncthreads();
        {
            const int row = t >> 4, c = t & 15;          // 16 rows x 16 writers
            const unsigned* p = &lds_t[row * 132 + c * 8];
            uint4 d0 = *(const uint4*)(p);
            uint4 d1 = *(const uint4*)(p + 4);
            unsigned short* hp = h1 + (size_t)(n0 + mm * 16 + row) * 256 + c * 16;
            *(uint4*)(hp) = d0;
            *(uint4*)(hp + 8) = d1;
        }
        __syncthreads();                                 // lds_t free for next half
    }
}

// ---------------- layer-1 aggregation ---------------------------------------
// wave per node; padded 64-slot edge table (beg = n<<6, cnt = deg[n]).
// NOTE (R1/R2 lessons): this 32-VGPR guarded schedule is a measured local
// optimum. Hand-batched gathers (+24 VGPR) -> occupancy 78->40%, slower.
// Unguarded loads + __launch_bounds__(256,8) -> acc[] spill (555 MB scratch
// writes), 2x slower. TLP is doing the latency hiding; leave the guard alone.
// R5: 4-way grid split costs ~45us -> single launch. R8: cooperative mega-
// kernel (capped resident grid) -> 2.8x slower; keep standalone.
__global__ __launch_bounds__(256) void k_l1agg(const unsigned short* __restrict__ h1,
                                               const float* __restrict__ a_src,
                                               const float* __restrict__ a_dst,
                                               const int* __restrict__ deg,
                                               const int* __restrict__ esrc,
                                               const float* __restrict__ b1,
                                               const float* __restrict__ W2,
                                               const float* __restrict__ att_s2,
                                               const float* __restrict__ att_d2,
                                               float4* __restrict__ node2) {
    const int t = threadIdx.x;
    const int n = blockIdx.x * 4 + (t >> 6);
    const int l = t & 63;
    const int q = l >> 4;       // quarter 0..3 (phase B)
    const int sl = l & 15;      // lane in quarter
    const int head = sl >> 2;
    const int c0 = sl * 16;
    const int el = l >> 2;      // phase-A edge slot 0..15
    const int hl = l & 3;       // phase-A head
    const int dg = deg[n];
    const int ebase = n << 6;
    const float4 ad4 = *(const float4*)&a_dst[n * 4];
    const float adh = (hl == 0) ? ad4.x : (hl == 1) ? ad4.y : (hl == 2) ? ad4.z : ad4.w;

    float ssum = 0.0f;
    float acc[16];
#pragma unroll
    for (int c = 0; c < 16; ++c) acc[c] = 0.0f;

    for (int base = 0; base < dg; base += 16) {
        const int cnt = dg - base;             // wave-uniform, > 0
        const int iters = (cnt < 16) ? cnt : 16;
        int sA = 0; float pA = 0.0f;
        if (el < cnt) {                        // phase A: 16 edges x 4 heads
            sA = esrc[ebase + base + el];
            const float a = a_src[sA * 4 + hl] + adh;
            const float e = (a > 0.0f) ? a : NEG * a;
            pA = __expf(e);
        }
#pragma unroll
        for (int jb = 0; jb < 16; jb += 4) {   // uniform 4 iterations, unrolled
            const int j = jb + q;              // this quarter's edge slot (<=15)
            const int s = __shfl(sA, j << 2);
            const float p = __shfl(pA, (j << 2) | head);
            if (j < iters) {                   // divergent guard: no cross-lane ops inside
                ssum += p;
                const unsigned ho = ((unsigned)s << 8) + c0;
                const uint4 hv0 = *(const uint4*)(h1 + ho);
                const uint4 hv1 = *(const uint4*)(h1 + ho + 8);
                acc[0]  += p * bflo(hv0.x); acc[1]  += p * bfhi(hv0.x);
                acc[2]  += p * bflo(hv0.y); acc[3]  += p * bfhi(hv0.y);
                acc[4]  += p * bflo(hv0.z); acc[5]  += p * bfhi(hv0.z);
                acc[6]  += p * bflo(hv0.w); acc[7]  += p * bfhi(hv0.w);
                acc[8]  += p * bflo(hv1.x); acc[9]  += p * bfhi(hv1.x);
                acc[10] += p * bflo(hv1.y); acc[11] += p * bfhi(hv1.y);
                acc[12] += p * bflo(hv1.z); acc[13] += p * bfhi(hv1.z);
                acc[14] += p * bflo(hv1.w); acc[15] += p * bfhi(hv1.w);
            }
        }
    }
    // merge quarters (lanes with same sl share channel set; quarter bits = 4,5)
    ssum += __shfl_xor(ssum, 16); ssum += __shfl_xor(ssum, 32);
#pragma unroll
    for (int c = 0; c < 16; ++c) {
        acc[c] += __shfl_xor(acc[c], 16);
        acc[c] += __shfl_xor(acc[c], 32);
    }
    const float inv = 1.0f / ssum;
    float p0 = 0.0f, p1 = 0.0f;
#pragma unroll
    for (int c = 0; c < 16; ++c) {
        const float v = fmaxf(acc[c] * inv + b1[c0 + c], 0.0f);
        p0 += v * W2[(c0 + c) * 2 + 0];
        p1 += v * W2[(c0 + c) * 2 + 1];
    }
    if (q) { p0 = 0.0f; p1 = 0.0f; }
#pragma unroll
    for (int off = 32; off; off >>= 1) {
        p0 += __shfl_down(p0, off);
        p1 += __shfl_down(p1, off);
    }
    if (l == 0) {
        const float as2v = p0 * att_s2[0] + p1 * att_s2[1];
        const float ad2v = p0 * att_d2[0] + p1 * att_d2[1];
        node2[n] = make_float4(p0, p1, as2v, ad2v);
    }
}

// ---------------- layer-2 aggregation + log_softmax (16 lanes per node) -----
__global__ __launch_bounds__(256) void k_l2agg(const float4* __restrict__ node2,
                                               const int* __restrict__ deg,
                                               const int* __restrict__ esrc,
                                               const float* __restrict__ b2,
                                               float* __restrict__ out) {
    const int t = threadIdx.x;
    const int l = t & 63;
    const int g = l >> 4;                       // node within wave (0..3)
    const int i = l & 15;                       // lane within node group
    const int n = blockIdx.x * 16 + (t >> 6) * 4 + g;
    const int dg = deg[n];
    const int ebase = n << 6;
    const float adst = node2[n].w;
    float ssum = 0.0f, a0 = 0.0f, a1 = 0.0f;
    for (int idx = i; idx < dg; idx += 16) {
        const int s = esrc[ebase + idx];
        const float4 r = node2[s];
        const float a = r.z + adst;
        const float e = (a > 0.0f) ? a : NEG * a;
        const float p = __expf(e);
        ssum += p; a0 += p * r.x; a1 += p * r.y;
    }
#pragma unroll
    for (int off = 8; off; off >>= 1) {         // reduce within 16-lane group
        ssum += __shfl_xor(ssum, off);
        a0 += __shfl_xor(a0, off);
        a1 += __shfl_xor(a1, off);
    }
    if (i == 0) {
        const float inv = 1.0f / ssum;
        const float z0 = a0 * inv + b2[0];
        const float z1 = a1 * inv + b2[1];
        const float mz = fmaxf(z0, z1);
        const float lse = mz + __logf(__expf(z0 - mz) + __expf(z1 - mz));
        out[n * 2 + 0] = z0 - lse;
        out[n * 2 + 1] = z1 - lse;
    }
}

extern "C" void kernel_launch(void* const* d_in, const int* in_sizes, int n_in,
                              void* d_out, int out_size, void* d_ws, size_t ws_size,
                              hipStream_t stream) {
    const float* x    = (const float*)d_in[0];
    const int*   src  = (const int*)d_in[1];
    const int*   dst  = (const int*)d_in[2];
    const float* W1   = (const float*)d_in[3];
    const float* as1w = (const float*)d_in[4];
    const float* ad1w = (const float*)d_in[5];
    const float* b1   = (const float*)d_in[6];
    const float* W2   = (const float*)d_in[7];
    const float* as2w = (const float*)d_in[8];
    const float* ad2w = (const float*)d_in[9];
    const float* b2   = (const float*)d_in[10];
    float* out = (float*)d_out;

    char* w = (char*)d_ws;
    unsigned short* h1  = (unsigned short*)w; w += (size_t)NN * 256 * 2;  // 51.2 MB
    unsigned short* Wt  = (unsigned short*)w; w += (size_t)256 * KP * 2;  // 98 KB
    float* a_src = (float*)w; w += (size_t)NN * 4 * 4;
    float* a_dst = (float*)w; w += (size_t)NN * 4 * 4;
    float4* node2 = (float4*)w; w += (size_t)NN * 4 * 4;
    int* deg     = (int*)w;   w += (size_t)NN * 4;
    int* esrc    = (int*)w;   w += (size_t)NN * SLOTS * 4;                // 25.6 MB

    k_prep<<<512, 256, 0, stream>>>(W1, Wt, deg, esrc);
    k_hsgemm<<<HS_BLKS + GEMM_BLKS, 256, 0, stream>>>(src, dst, x, Wt, as1w, ad1w,
                                                      deg, esrc, h1, a_src, a_dst);
    k_l1agg<<<NN / 4, 256, 0, stream>>>(h1, a_src, a_dst, deg, esrc, b1, W2, as2w, ad2w, node2);
    k_l2agg<<<NN / 16, 256, 0, stream>>>(node2, deg, esrc, b2, out);
}

// Round 13
// 435.775 us; speedup vs baseline: 1.0574x; 1.0374x over previous
//
#include <hip/hip_runtime.h>
#include <math.h>

#define NN 100000
#define NE 1600000
#define ET (NE + NN)            // 1,700,000 edges incl. self-loops
#define NEG 0.2f
#define KP 192                  // padded K for MFMA (165 -> 192)
#define GEMM_BLKS (NN / 32)     // 3125
#define SLOTS 64                // fixed edge slots per node (P(deg>63) ~ 1e-25)
#define NPART 8                 // dst-range partitions
#define PART_SZ (NN / NPART)    // 12500
#define NCHUNK 1024
#define CH ((NE + NCHUNK - 1) / NCHUNK)   // 1563 edges per chunk
#define HS_BLKS (NPART * NCHUNK)          // 8192 histscat role blocks
#define LDA 200                 // LDS A-tile row stride in bf16 (400B rows)

typedef __attribute__((ext_vector_type(8))) short short8;
typedef __attribute__((ext_vector_type(4))) float floatx4;

// bf16 helpers (round-to-nearest-even)
__device__ __forceinline__ unsigned short f2bf(float f) {
    unsigned u = __float_as_uint(f);
    unsigned r = u + 0x7fffu + ((u >> 16) & 1u);
    return (unsigned short)(r >> 16);
}
__device__ __forceinline__ float bflo(unsigned x) { return __uint_as_float(x << 16); }
__device__ __forceinline__ float bfhi(unsigned x) { return __uint_as_float(x & 0xFFFF0000u); }

// ---------------- prep: Wt bf16 [256][KP], deg=1 + self-loop slot0 -----------
__global__ __launch_bounds__(256) void k_prep(const float* __restrict__ W,
                                              unsigned short* __restrict__ Wt,
                                              int* __restrict__ deg,
                                              int* __restrict__ esrc) {
    const int gid = blockIdx.x * 256 + threadIdx.x;
    const int G = gridDim.x * 256;
    for (int idx = gid; idx < 256 * KP; idx += G) {
        const int n = idx / KP, k = idx - n * KP;
        Wt[idx] = (k < 165) ? f2bf(W[k * 256 + n]) : (unsigned short)0;
    }
    // self-loop pre-placed at slot 0: removes 100K edges from the scatter
    for (int i = gid; i < NN; i += G) { deg[i] = 1; esrc[i << 6] = i; }
}

// ---------------- fused histscat + GEMM1 (block-role split) ------------------
// History: R9 (64 VGPR, 41% occ) 182us; R10 ((256,5), single-bf, ~48 VGPR)
// ~168us, total 411.4 = best; R11 (direct 32B stores) 188us +74MB writes;
// R12 (half-tile, 40 VGPR, 60% occ) 183us. Lesson: occupancy is NOT the
// scatter's lever (60% occ == 41% occ in time); the fused kernel sits at
// ~180+-8 for all knob settings, R10's config being the best sample. So:
// exact R10 structure restored. R13's single change: GEMM ROLE DISPATCHES
// FIRST (b < GEMM_BLKS) so the kernel tail is scatter (the long pole), not
// ~2 residency-rounds of pure gemm after the scatter drains.
// R8 lesson: NOT cooperative; oversubscribed block churn is the TLP resource.
__global__ __launch_bounds__(256, 5) void k_hsgemm(const int* __restrict__ src,
                                                const int* __restrict__ dst,
                                                const float* __restrict__ x,
                                                const unsigned short* __restrict__ Wt,
                                                const float* __restrict__ att_s,
                                                const float* __restrict__ att_d,
                                                int* __restrict__ deg,
                                                int* __restrict__ esrc,
                                                unsigned short* __restrict__ h1,
                                                float* __restrict__ a_src,
                                                float* __restrict__ a_dst) {
    __shared__ __align__(16) unsigned lds_u32[32 * 132];   // 16.9 KB, dual-use
    const int t = threadIdx.x;
    const int b = blockIdx.x;

    if (b >= GEMM_BLKS) {
        // ---- histscat role (R6 dst-range partitioned, b&7) ----
        const int sb = b - GEMM_BLKS;
        const int p = sb & 7;
        const int chunk = sb >> 3;
        const int e0 = chunk * CH;
        const int e1 = (e0 + CH < NE) ? e0 + CH : NE;
        const int plo = p * PART_SZ, phi = plo + PART_SZ;
        for (int e = e0 + t; e < e1; e += 256) {
            const int d = dst[e];
            if (d >= plo && d < phi) {
                const int s = src[e];
                const int r = atomicAdd(&deg[d], 1);
                if (r < SLOTS) esrc[(d << 6) + r] = s;
            }
        }
        return;
    }

    // ---- gemm role: one 32-node tile (dispatches FIRST, R13) ----
    const int n0 = b * 32;
    unsigned short* lds_a = (unsigned short*)lds_u32;      // [32][LDA] bf16 A-tile

    // stage x rows (coalesced, convert once) + zero the K-pad
    for (int i = t; i < 32 * 165; i += 256) {
        const int n = i / 165, k = i - n * 165;
        lds_a[n * LDA + k] = f2bf(x[(size_t)(n0 + n) * 165 + k]);
    }
    for (int i = t; i < 32 * (LDA - 165); i += 256) {      // k = 165..LDA-1 -> 0
        const int n = i / (LDA - 165), k = 165 + (i - n * (LDA - 165));
        lds_a[n * LDA + k] = 0;
    }
    __syncthreads();

    const int lane = t & 63, hd = t >> 6;
    const int r16 = lane & 15, quad = lane >> 4;
    floatx4 zero4 = {0.0f, 0.0f, 0.0f, 0.0f};
    floatx4 acc[2][4];
#pragma unroll
    for (int mm = 0; mm < 2; ++mm)
#pragma unroll
        for (int nn = 0; nn < 4; ++nn) acc[mm][nn] = zero4;

    const unsigned short* ar0 = lds_a + r16 * LDA;
    const unsigned short* ar1 = lds_a + (16 + r16) * LDA;
#pragma unroll
    for (int ks = 0; ks < 6; ++ks) {
        const int kb = ks * 32 + quad * 8;
        short8 a0 = *(const short8*)(ar0 + kb);
        short8 a1 = *(const short8*)(ar1 + kb);
#pragma unroll
        for (int nn = 0; nn < 4; ++nn) {       // single B-frag live (VGPR diet)
            short8 bf = *(const short8*)(Wt + (size_t)(hd * 64 + nn * 16 + r16) * KP + kb);
            acc[0][nn] = __builtin_amdgcn_mfma_f32_16x16x32_bf16(a0, bf, acc[0][nn], 0, 0, 0);
            acc[1][nn] = __builtin_amdgcn_mfma_f32_16x16x32_bf16(a1, bf, acc[1][nn], 0, 0, 0);
        }
    }

    float asw[4], adw[4];
#pragma unroll
    for (int nn = 0; nn < 4; ++nn) {
        asw[nn] = att_s[hd * 64 + nn * 16 + r16];
        adw[nn] = att_d[hd * 64 + nn * 16 + r16];
    }
#pragma unroll
    for (int mm = 0; mm < 2; ++mm)
#pragma unroll
        for (int r = 0; r < 4; ++r) {
            float ps = acc[mm][0][r] * asw[0] + acc[mm][1][r] * asw[1] +
                       acc[mm][2][r] * asw[2] + acc[mm][3][r] * asw[3];
            float pd = acc[mm][0][r] * adw[0] + acc[mm][1][r] * adw[1] +
                       acc[mm][2][r] * adw[2] + acc[mm][3][r] * adw[3];
            ps += __shfl_xor(ps, 1); ps += __shfl_xor(ps, 2);
            ps += __shfl_xor(ps, 4); ps += __shfl_xor(ps, 8);
            pd += __shfl_xor(pd, 1); pd += __shfl_xor(pd, 2);
            pd += __shfl_xor(pd, 4); pd += __shfl_xor(pd, 8);
            if (r16 == 0) {
                const int node = n0 + mm * 16 + quad * 4 + r;
                a_src[node * 4 + hd] = ps;
                a_dst[node * 4 + hd] = pd;
            }
        }

    __syncthreads();   // A-tile reads done; reuse lds_u32 for epilogue transpose
#pragma unroll
    for (int mm = 0; mm < 2; ++mm)
#pragma unroll
        for (int nn = 0; nn < 4; ++nn)
#pragma unroll
            for (int r = 0; r < 4; ++r) {
                const float v = acc[mm][nn][r];
                const float o = __shfl_xor(v, 1);
                if ((lane & 1) == 0) {
                    const unsigned pk = (unsigned)f2bf(v) | ((unsigned)f2bf(o) << 16);
                    lds_u32[(mm * 16 + quad * 4 + r) * 132 + hd * 32 + nn * 8 + (r16 >> 1)] = pk;
                }
            }
    __syncthreads();
    {
        const int row = t & 31, seg = t >> 5;
        const unsigned* p = &lds_u32[row * 132 + seg * 16];
        uint4 d0 = *(const uint4*)(p);
        uint4 d1 = *(const uint4*)(p + 4);
        uint4 d2 = *(const uint4*)(p + 8);
        uint4 d3 = *(const uint4*)(p + 12);
        unsigned short* hp = h1 + (size_t)(n0 + row) * 256 + seg * 32;
        *(uint4*)(hp) = d0;
        *(uint4*)(hp + 8) = d1;
        *(uint4*)(hp + 16) = d2;
        *(uint4*)(hp + 24) = d3;
    }
}

// ---------------- layer-1 aggregation ---------------------------------------
// wave per node; padded 64-slot edge table (beg = n<<6, cnt = deg[n]).
// NOTE (R1/R2 lessons): this 32-VGPR guarded schedule is a measured local
// optimum. Hand-batched gathers (+24 VGPR) -> occupancy 78->40%, slower.
// Unguarded loads + __launch_bounds__(256,8) -> acc[] spill (555 MB scratch
// writes), 2x slower. TLP is doing the latency hiding; leave the guard alone.
// R5: 4-way grid split costs ~45us -> single launch. R8: cooperative mega-
// kernel (capped resident grid) -> 2.8x slower; keep standalone.
__global__ __launch_bounds__(256) void k_l1agg(const unsigned short* __restrict__ h1,
                                               const float* __restrict__ a_src,
                                               const float* __restrict__ a_dst,
                                               const int* __restrict__ deg,
                                               const int* __restrict__ esrc,
                                               const float* __restrict__ b1,
                                               const float* __restrict__ W2,
                                               const float* __restrict__ att_s2,
                                               const float* __restrict__ att_d2,
                                               float4* __restrict__ node2) {
    const int t = threadIdx.x;
    const int n = blockIdx.x * 4 + (t >> 6);
    const int l = t & 63;
    const int q = l >> 4;       // quarter 0..3 (phase B)
    const int sl = l & 15;      // lane in quarter
    const int head = sl >> 2;
    const int c0 = sl * 16;
    const int el = l >> 2;      // phase-A edge slot 0..15
    const int hl = l & 3;       // phase-A head
    const int dg = deg[n];
    const int ebase = n << 6;
    const float4 ad4 = *(const float4*)&a_dst[n * 4];
    const float adh = (hl == 0) ? ad4.x : (hl == 1) ? ad4.y : (hl == 2) ? ad4.z : ad4.w;

    float ssum = 0.0f;
    float acc[16];
#pragma unroll
    for (int c = 0; c < 16; ++c) acc[c] = 0.0f;

    for (int base = 0; base < dg; base += 16) {
        const int cnt = dg - base;             // wave-uniform, > 0
        const int iters = (cnt < 16) ? cnt : 16;
        int sA = 0; float pA = 0.0f;
        if (el < cnt) {                        // phase A: 16 edges x 4 heads
            sA = esrc[ebase + base + el];
            const float a = a_src[sA * 4 + hl] + adh;
            const float e = (a > 0.0f) ? a : NEG * a;
            pA = __expf(e);
        }
#pragma unroll
        for (int jb = 0; jb < 16; jb += 4) {   // uniform 4 iterations, unrolled
            const int j = jb + q;              // this quarter's edge slot (<=15)
            const int s = __shfl(sA, j << 2);
            const float p = __shfl(pA, (j << 2) | head);
            if (j < iters) {                   // divergent guard: no cross-lane ops inside
                ssum += p;
                const unsigned ho = ((unsigned)s << 8) + c0;
                const uint4 hv0 = *(const uint4*)(h1 + ho);
                const uint4 hv1 = *(const uint4*)(h1 + ho + 8);
                acc[0]  += p * bflo(hv0.x); acc[1]  += p * bfhi(hv0.x);
                acc[2]  += p * bflo(hv0.y); acc[3]  += p * bfhi(hv0.y);
                acc[4]  += p * bflo(hv0.z); acc[5]  += p * bfhi(hv0.z);
                acc[6]  += p * bflo(hv0.w); acc[7]  += p * bfhi(hv0.w);
                acc[8]  += p * bflo(hv1.x); acc[9]  += p * bfhi(hv1.x);
                acc[10] += p * bflo(hv1.y); acc[11] += p * bfhi(hv1.y);
                acc[12] += p * bflo(hv1.z); acc[13] += p * bfhi(hv1.z);
                acc[14] += p * bflo(hv1.w); acc[15] += p * bfhi(hv1.w);
            }
        }
    }
    // merge quarters (lanes with same sl share channel set; quarter bits = 4,5)
    ssum += __shfl_xor(ssum, 16); ssum += __shfl_xor(ssum, 32);
#pragma unroll
    for (int c = 0; c < 16; ++c) {
        acc[c] += __shfl_xor(acc[c], 16);
        acc[c] += __shfl_xor(acc[c], 32);
    }
    const float inv = 1.0f / ssum;
    float p0 = 0.0f, p1 = 0.0f;
#pragma unroll
    for (int c = 0; c < 16; ++c) {
        const float v = fmaxf(acc[c] * inv + b1[c0 + c], 0.0f);
        p0 += v * W2[(c0 + c) * 2 + 0];
        p1 += v * W2[(c0 + c) * 2 + 1];
    }
    if (q) { p0 = 0.0f; p1 = 0.0f; }
#pragma unroll
    for (int off = 32; off; off >>= 1) {
        p0 += __shfl_down(p0, off);
        p1 += __shfl_down(p1, off);
    }
    if (l == 0) {
        const float as2v = p0 * att_s2[0] + p1 * att_s2[1];
        const float ad2v = p0 * att_d2[0] + p1 * att_d2[1];
        node2[n] = make_float4(p0, p1, as2v, ad2v);
    }
}

// ---------------- layer-2 aggregation + log_softmax (16 lanes per node) -----
__global__ __launch_bounds__(256) void k_l2agg(const float4* __restrict__ node2,
                                               const int* __restrict__ deg,
                                               const int* __restrict__ esrc,
                                               const float* __restrict__ b2,
                                               float* __restrict__ out) {
    const int t = threadIdx.x;
    const int l = t & 63;
    const int g = l >> 4;                       // node within wave (0..3)
    const int i = l & 15;                       // lane within node group
    const int n = blockIdx.x * 16 + (t >> 6) * 4 + g;
    const int dg = deg[n];
    const int ebase = n << 6;
    const float adst = node2[n].w;
    float ssum = 0.0f, a0 = 0.0f, a1 = 0.0f;
    for (int idx = i; idx < dg; idx += 16) {
        const int s = esrc[ebase + idx];
        const float4 r = node2[s];
        const float a = r.z + adst;
        const float e = (a > 0.0f) ? a : NEG * a;
        const float p = __expf(e);
        ssum += p; a0 += p * r.x; a1 += p * r.y;
    }
#pragma unroll
    for (int off = 8; off; off >>= 1) {         // reduce within 16-lane group
        ssum += __shfl_xor(ssum, off);
        a0 += __shfl_xor(a0, off);
        a1 += __shfl_xor(a1, off);
    }
    if (i == 0) {
        const float inv = 1.0f / ssum;
        const float z0 = a0 * inv + b2[0];
        const float z1 = a1 * inv + b2[1];
        const float mz = fmaxf(z0, z1);
        const float lse = mz + __logf(__expf(z0 - mz) + __expf(z1 - mz));
        out[n * 2 + 0] = z0 - lse;
        out[n * 2 + 1] = z1 - lse;
    }
}

extern "C" void kernel_launch(void* const* d_in, const int* in_sizes, int n_in,
                              void* d_out, int out_size, void* d_ws, size_t ws_size,
                              hipStream_t stream) {
    const float* x    = (const float*)d_in[0];
    const int*   src  = (const int*)d_in[1];
    const int*   dst  = (const int*)d_in[2];
    const float* W1   = (const float*)d_in[3];
    const float* as1w = (const float*)d_in[4];
    const float* ad1w = (const float*)d_in[5];
    const float* b1   = (const float*)d_in[6];
    const float* W2   = (const float*)d_in[7];
    const float* as2w = (const float*)d_in[8];
    const float* ad2w = (const float*)d_in[9];
    const float* b2   = (const float*)d_in[10];
    float* out = (float*)d_out;

    char* w = (char*)d_ws;
    unsigned short* h1  = (unsigned short*)w; w += (size_t)NN * 256 * 2;  // 51.2 MB
    unsigned short* Wt  = (unsigned short*)w; w += (size_t)256 * KP * 2;  // 98 KB
    float* a_src = (float*)w; w += (size_t)NN * 4 * 4;
    float* a_dst = (float*)w; w += (size_t)NN * 4 * 4;
    float4* node2 = (float4*)w; w += (size_t)NN * 4 * 4;
    int* deg     = (int*)w;   w += (size_t)NN * 4;
    int* esrc    = (int*)w;   w += (size_t)NN * SLOTS * 4;                // 25.6 MB

    k_prep<<<512, 256, 0, stream>>>(W1, Wt, deg, esrc);
    k_hsgemm<<<HS_BLKS + GEMM_BLKS, 256, 0, stream>>>(src, dst, x, Wt, as1w, ad1w,
                                                      deg, esrc, h1, a_src, a_dst);
    k_l1agg<<<NN / 4, 256, 0, stream>>>(h1, a_src, a_dst, deg, esrc, b1, W2, as2w, ad2w, node2);
    k_l2agg<<<NN / 16, 256, 0, stream>>>(node2, deg, esrc, b2, out);
}

// Round 14
// 413.135 us; speedup vs baseline: 1.1154x; 1.0548x over previous
//
#include <hip/hip_runtime.h>
#include <math.h>

#define NN 100000
#define NE 1600000
#define ET (NE + NN)            // 1,700,000 edges incl. self-loops
#define NEG 0.2f
#define KP 192                  // padded K for MFMA (165 -> 192)
#define GEMM_BLKS (NN / 32)     // 3125
#define SLOTS 64                // fixed edge slots per node (P(deg>63) ~ 1e-25)
#define NPART 8                 // dst-range partitions
#define PART_SZ (NN / NPART)    // 12500
#define NCHUNK 1024
#define CH ((NE + NCHUNK - 1) / NCHUNK)   // 1563 edges per chunk
#define HS_BLKS (NPART * NCHUNK)          // 8192 histscat role blocks
#define LDA 200                 // LDS A-tile row stride in bf16 (400B rows)

typedef __attribute__((ext_vector_type(8))) short short8;
typedef __attribute__((ext_vector_type(4))) float floatx4;

// bf16 helpers (round-to-nearest-even)
__device__ __forceinline__ unsigned short f2bf(float f) {
    unsigned u = __float_as_uint(f);
    unsigned r = u + 0x7fffu + ((u >> 16) & 1u);
    return (unsigned short)(r >> 16);
}
__device__ __forceinline__ float bflo(unsigned x) { return __uint_as_float(x << 16); }
__device__ __forceinline__ float bfhi(unsigned x) { return __uint_as_float(x & 0xFFFF0000u); }

// ---------------- prep: Wt bf16 [256][KP], deg=1 + self-loop slot0 -----------
__global__ __launch_bounds__(256) void k_prep(const float* __restrict__ W,
                                              unsigned short* __restrict__ Wt,
                                              int* __restrict__ deg,
                                              int* __restrict__ esrc) {
    const int gid = blockIdx.x * 256 + threadIdx.x;
    const int G = gridDim.x * 256;
    for (int idx = gid; idx < 256 * KP; idx += G) {
        const int n = idx / KP, k = idx - n * KP;
        Wt[idx] = (k < 165) ? f2bf(W[k * 256 + n]) : (unsigned short)0;
    }
    // self-loop pre-placed at slot 0: removes 100K edges from the scatter
    for (int i = gid; i < NN; i += G) { deg[i] = 1; esrc[i << 6] = i; }
}

// ---------------- fused histscat + GEMM1 (block-role split) ------------------
// EXACT R10 configuration (best measured: 411.4us total). History:
//   R9  (bfv[4], 64 VGPR, 41% occ)            hsgemm 182us
//   R10 ((256,5), single-bf, ~48 VGPR)        hsgemm ~168us  <- BEST
//   R11 (direct 32B h1 stores)                188us, WRITE +74MB (amplification)
//   R12 (half-tile, 40 VGPR, 60% occ)         183us (occupancy is NOT the lever)
//   R13 (gemm-role dispatches first)          total +24us -- delaying the
//        scatter (the critical path) start costs one-for-one; scatter-first
//        with gemm backfilling its latency bubbles is the right orientation.
// R8 lesson: NOT cooperative; oversubscribed block churn is the TLP resource.
__global__ __launch_bounds__(256, 5) void k_hsgemm(const int* __restrict__ src,
                                                const int* __restrict__ dst,
                                                const float* __restrict__ x,
                                                const unsigned short* __restrict__ Wt,
                                                const float* __restrict__ att_s,
                                                const float* __restrict__ att_d,
                                                int* __restrict__ deg,
                                                int* __restrict__ esrc,
                                                unsigned short* __restrict__ h1,
                                                float* __restrict__ a_src,
                                                float* __restrict__ a_dst) {
    __shared__ __align__(16) unsigned lds_u32[32 * 132];   // 16.9 KB, dual-use
    const int t = threadIdx.x;
    const int b = blockIdx.x;

    if (b < HS_BLKS) {
        // ---- histscat role (R6 dst-range partitioned; dispatches FIRST) ----
        const int p = b & 7;
        const int chunk = b >> 3;
        const int e0 = chunk * CH;
        const int e1 = (e0 + CH < NE) ? e0 + CH : NE;
        const int plo = p * PART_SZ, phi = plo + PART_SZ;
        for (int e = e0 + t; e < e1; e += 256) {
            const int d = dst[e];
            if (d >= plo && d < phi) {
                const int s = src[e];
                const int r = atomicAdd(&deg[d], 1);
                if (r < SLOTS) esrc[(d << 6) + r] = s;
            }
        }
        return;
    }

    // ---- gemm role: one 32-node tile ----
    const int n0 = (b - HS_BLKS) * 32;
    unsigned short* lds_a = (unsigned short*)lds_u32;      // [32][LDA] bf16 A-tile

    // stage x rows (coalesced, convert once) + zero the K-pad
    for (int i = t; i < 32 * 165; i += 256) {
        const int n = i / 165, k = i - n * 165;
        lds_a[n * LDA + k] = f2bf(x[(size_t)(n0 + n) * 165 + k]);
    }
    for (int i = t; i < 32 * (LDA - 165); i += 256) {      // k = 165..LDA-1 -> 0
        const int n = i / (LDA - 165), k = 165 + (i - n * (LDA - 165));
        lds_a[n * LDA + k] = 0;
    }
    __syncthreads();

    const int lane = t & 63, hd = t >> 6;
    const int r16 = lane & 15, quad = lane >> 4;
    floatx4 zero4 = {0.0f, 0.0f, 0.0f, 0.0f};
    floatx4 acc[2][4];
#pragma unroll
    for (int mm = 0; mm < 2; ++mm)
#pragma unroll
        for (int nn = 0; nn < 4; ++nn) acc[mm][nn] = zero4;

    const unsigned short* ar0 = lds_a + r16 * LDA;
    const unsigned short* ar1 = lds_a + (16 + r16) * LDA;
#pragma unroll
    for (int ks = 0; ks < 6; ++ks) {
        const int kb = ks * 32 + quad * 8;
        short8 a0 = *(const short8*)(ar0 + kb);
        short8 a1 = *(const short8*)(ar1 + kb);
#pragma unroll
        for (int nn = 0; nn < 4; ++nn) {       // single B-frag live (VGPR diet)
            short8 bf = *(const short8*)(Wt + (size_t)(hd * 64 + nn * 16 + r16) * KP + kb);
            acc[0][nn] = __builtin_amdgcn_mfma_f32_16x16x32_bf16(a0, bf, acc[0][nn], 0, 0, 0);
            acc[1][nn] = __builtin_amdgcn_mfma_f32_16x16x32_bf16(a1, bf, acc[1][nn], 0, 0, 0);
        }
    }

    float asw[4], adw[4];
#pragma unroll
    for (int nn = 0; nn < 4; ++nn) {
        asw[nn] = att_s[hd * 64 + nn * 16 + r16];
        adw[nn] = att_d[hd * 64 + nn * 16 + r16];
    }
#pragma unroll
    for (int mm = 0; mm < 2; ++mm)
#pragma unroll
        for (int r = 0; r < 4; ++r) {
            float ps = acc[mm][0][r] * asw[0] + acc[mm][1][r] * asw[1] +
                       acc[mm][2][r] * asw[2] + acc[mm][3][r] * asw[3];
            float pd = acc[mm][0][r] * adw[0] + acc[mm][1][r] * adw[1] +
                       acc[mm][2][r] * adw[2] + acc[mm][3][r] * adw[3];
            ps += __shfl_xor(ps, 1); ps += __shfl_xor(ps, 2);
            ps += __shfl_xor(ps, 4); ps += __shfl_xor(ps, 8);
            pd += __shfl_xor(pd, 1); pd += __shfl_xor(pd, 2);
            pd += __shfl_xor(pd, 4); pd += __shfl_xor(pd, 8);
            if (r16 == 0) {
                const int node = n0 + mm * 16 + quad * 4 + r;
                a_src[node * 4 + hd] = ps;
                a_dst[node * 4 + hd] = pd;
            }
        }

    __syncthreads();   // A-tile reads done; reuse lds_u32 for epilogue transpose
#pragma unroll
    for (int mm = 0; mm < 2; ++mm)
#pragma unroll
        for (int nn = 0; nn < 4; ++nn)
#pragma unroll
            for (int r = 0; r < 4; ++r) {
                const float v = acc[mm][nn][r];
                const float o = __shfl_xor(v, 1);
                if ((lane & 1) == 0) {
                    const unsigned pk = (unsigned)f2bf(v) | ((unsigned)f2bf(o) << 16);
                    lds_u32[(mm * 16 + quad * 4 + r) * 132 + hd * 32 + nn * 8 + (r16 >> 1)] = pk;
                }
            }
    __syncthreads();
    {
        const int row = t & 31, seg = t >> 5;
        const unsigned* p = &lds_u32[row * 132 + seg * 16];
        uint4 d0 = *(const uint4*)(p);
        uint4 d1 = *(const uint4*)(p + 4);
        uint4 d2 = *(const uint4*)(p + 8);
        uint4 d3 = *(const uint4*)(p + 12);
        unsigned short* hp = h1 + (size_t)(n0 + row) * 256 + seg * 32;
        *(uint4*)(hp) = d0;
        *(uint4*)(hp + 8) = d1;
        *(uint4*)(hp + 16) = d2;
        *(uint4*)(hp + 24) = d3;
    }
}

// ---------------- layer-1 aggregation ---------------------------------------
// wave per node; padded 64-slot edge table (beg = n<<6, cnt = deg[n]).
// NOTE (R1/R2 lessons): this 32-VGPR guarded schedule is a measured local
// optimum. Hand-batched gathers (+24 VGPR) -> occupancy 78->40%, slower.
// Unguarded loads + __launch_bounds__(256,8) -> acc[] spill (555 MB scratch
// writes), 2x slower. TLP is doing the latency hiding; leave the guard alone.
// R5: 4-way grid split costs ~45us -> single launch. R8: cooperative mega-
// kernel (capped resident grid) -> 2.8x slower; keep standalone.
__global__ __launch_bounds__(256) void k_l1agg(const unsigned short* __restrict__ h1,
                                               const float* __restrict__ a_src,
                                               const float* __restrict__ a_dst,
                                               const int* __restrict__ deg,
                                               const int* __restrict__ esrc,
                                               const float* __restrict__ b1,
                                               const float* __restrict__ W2,
                                               const float* __restrict__ att_s2,
                                               const float* __restrict__ att_d2,
                                               float4* __restrict__ node2) {
    const int t = threadIdx.x;
    const int n = blockIdx.x * 4 + (t >> 6);
    const int l = t & 63;
    const int q = l >> 4;       // quarter 0..3 (phase B)
    const int sl = l & 15;      // lane in quarter
    const int head = sl >> 2;
    const int c0 = sl * 16;
    const int el = l >> 2;      // phase-A edge slot 0..15
    const int hl = l & 3;       // phase-A head
    const int dg = deg[n];
    const int ebase = n << 6;
    const float4 ad4 = *(const float4*)&a_dst[n * 4];
    const float adh = (hl == 0) ? ad4.x : (hl == 1) ? ad4.y : (hl == 2) ? ad4.z : ad4.w;

    float ssum = 0.0f;
    float acc[16];
#pragma unroll
    for (int c = 0; c < 16; ++c) acc[c] = 0.0f;

    for (int base = 0; base < dg; base += 16) {
        const int cnt = dg - base;             // wave-uniform, > 0
        const int iters = (cnt < 16) ? cnt : 16;
        int sA = 0; float pA = 0.0f;
        if (el < cnt) {                        // phase A: 16 edges x 4 heads
            sA = esrc[ebase + base + el];
            const float a = a_src[sA * 4 + hl] + adh;
            const float e = (a > 0.0f) ? a : NEG * a;
            pA = __expf(e);
        }
#pragma unroll
        for (int jb = 0; jb < 16; jb += 4) {   // uniform 4 iterations, unrolled
            const int j = jb + q;              // this quarter's edge slot (<=15)
            const int s = __shfl(sA, j << 2);
            const float p = __shfl(pA, (j << 2) | head);
            if (j < iters) {                   // divergent guard: no cross-lane ops inside
                ssum += p;
                const unsigned ho = ((unsigned)s << 8) + c0;
                const uint4 hv0 = *(const uint4*)(h1 + ho);
                const uint4 hv1 = *(const uint4*)(h1 + ho + 8);
                acc[0]  += p * bflo(hv0.x); acc[1]  += p * bfhi(hv0.x);
                acc[2]  += p * bflo(hv0.y); acc[3]  += p * bfhi(hv0.y);
                acc[4]  += p * bflo(hv0.z); acc[5]  += p * bfhi(hv0.z);
                acc[6]  += p * bflo(hv0.w); acc[7]  += p * bfhi(hv0.w);
                acc[8]  += p * bflo(hv1.x); acc[9]  += p * bfhi(hv1.x);
                acc[10] += p * bflo(hv1.y); acc[11] += p * bfhi(hv1.y);
                acc[12] += p * bflo(hv1.z); acc[13] += p * bfhi(hv1.z);
                acc[14] += p * bflo(hv1.w); acc[15] += p * bfhi(hv1.w);
            }
        }
    }
    // merge quarters (lanes with same sl share channel set; quarter bits = 4,5)
    ssum += __shfl_xor(ssum, 16); ssum += __shfl_xor(ssum, 32);
#pragma unroll
    for (int c = 0; c < 16; ++c) {
        acc[c] += __shfl_xor(acc[c], 16);
        acc[c] += __shfl_xor(acc[c], 32);
    }
    const float inv = 1.0f / ssum;
    float p0 = 0.0f, p1 = 0.0f;
#pragma unroll
    for (int c = 0; c < 16; ++c) {
        const float v = fmaxf(acc[c] * inv + b1[c0 + c], 0.0f);
        p0 += v * W2[(c0 + c) * 2 + 0];
        p1 += v * W2[(c0 + c) * 2 + 1];
    }
    if (q) { p0 = 0.0f; p1 = 0.0f; }
#pragma unroll
    for (int off = 32; off; off >>= 1) {
        p0 += __shfl_down(p0, off);
        p1 += __shfl_down(p1, off);
    }
    if (l == 0) {
        const float as2v = p0 * att_s2[0] + p1 * att_s2[1];
        const float ad2v = p0 * att_d2[0] + p1 * att_d2[1];
        node2[n] = make_float4(p0, p1, as2v, ad2v);
    }
}

// ---------------- layer-2 aggregation + log_softmax (16 lanes per node) -----
__global__ __launch_bounds__(256) void k_l2agg(const float4* __restrict__ node2,
                                               const int* __restrict__ deg,
                                               const int* __restrict__ esrc,
                                               const float* __restrict__ b2,
                                               float* __restrict__ out) {
    const int t = threadIdx.x;
    const int l = t & 63;
    const int g = l >> 4;                       // node within wave (0..3)
    const int i = l & 15;                       // lane within node group
    const int n = blockIdx.x * 16 + (t >> 6) * 4 + g;
    const int dg = deg[n];
    const int ebase = n << 6;
    const float adst = node2[n].w;
    float ssum = 0.0f, a0 = 0.0f, a1 = 0.0f;
    for (int idx = i; idx < dg; idx += 16) {
        const int s = esrc[ebase + idx];
        const float4 r = node2[s];
        const float a = r.z + adst;
        const float e = (a > 0.0f) ? a : NEG * a;
        const float p = __expf(e);
        ssum += p; a0 += p * r.x; a1 += p * r.y;
    }
#pragma unroll
    for (int off = 8; off; off >>= 1) {         // reduce within 16-lane group
        ssum += __shfl_xor(ssum, off);
        a0 += __shfl_xor(a0, off);
        a1 += __shfl_xor(a1, off);
    }
    if (i == 0) {
        const float inv = 1.0f / ssum;
        const float z0 = a0 * inv + b2[0];
        const float z1 = a1 * inv + b2[1];
        const float mz = fmaxf(z0, z1);
        const float lse = mz + __logf(__expf(z0 - mz) + __expf(z1 - mz));
        out[n * 2 + 0] = z0 - lse;
        out[n * 2 + 1] = z1 - lse;
    }
}

extern "C" void kernel_launch(void* const* d_in, const int* in_sizes, int n_in,
                              void* d_out, int out_size, void* d_ws, size_t ws_size,
                              hipStream_t stream) {
    const float* x    = (const float*)d_in[0];
    const int*   src  = (const int*)d_in[1];
    const int*   dst  = (const int*)d_in[2];
    const float* W1   = (const float*)d_in[3];
    const float* as1w = (const float*)d_in[4];
    const float* ad1w = (const float*)d_in[5];
    const float* b1   = (const float*)d_in[6];
    const float* W2   = (const float*)d_in[7];
    const float* as2w = (const float*)d_in[8];
    const float* ad2w = (const float*)d_in[9];
    const float* b2   = (const float*)d_in[10];
    float* out = (float*)d_out;

    char* w = (char*)d_ws;
    unsigned short* h1  = (unsigned short*)w; w += (size_t)NN * 256 * 2;  // 51.2 MB
    unsigned short* Wt  = (unsigned short*)w; w += (size_t)256 * KP * 2;  // 98 KB
    float* a_src = (float*)w; w += (size_t)NN * 4 * 4;
    float* a_dst = (float*)w; w += (size_t)NN * 4 * 4;
    float4* node2 = (float4*)w; w += (size_t)NN * 4 * 4;
    int* deg     = (int*)w;   w += (size_t)NN * 4;
    int* esrc    = (int*)w;   w += (size_t)NN * SLOTS * 4;                // 25.6 MB

    k_prep<<<512, 256, 0, stream>>>(W1, Wt, deg, esrc);
    k_hsgemm<<<HS_BLKS + GEMM_BLKS, 256, 0, stream>>>(src, dst, x, Wt, as1w, ad1w,
                                                      deg, esrc, h1, a_src, a_dst);
    k_l1agg<<<NN / 4, 256, 0, stream>>>(h1, a_src, a_dst, deg, esrc, b1, W2, as2w, ad2w, node2);
    k_l2agg<<<NN / 16, 256, 0, stream>>>(node2, deg, esrc, b2, out);
}